// Round 1
// baseline (1246.151 us; speedup 1.0000x reference)
//
#include <hip/hip_runtime.h>
#include <cmath>

#pragma clang fp contract(off)

#define NPRIORS 131072
#define NIMG 16
#define KSEL 5000
#define TOPK 750
#define SORTN 8192
#define NBINS 1024
#define NSUB 8
#define NMASK ((KSEL + 63) / 64)   // 79

// ---------------- workspace layout ----------------
// pairs   : u64  [NIMG][SORTN]   offset 0          size 1,048,576
// mcount  : int  [NIMG]          offset 1,048,576  size 64 (pad 256)
// sboxes  : f4   [NIMG][KSEL]    offset 1,048,832  size 1,280,000
// sscores : f32  [NIMG][KSEL]    offset 2,328,832  size 320,000
#define WS_PAIRS 0
#define WS_MCNT 1048576
#define WS_BOXES 1048832
#define WS_SCORES 2328832

// ============ Kernel 1: exact top-KSEL selection via 2-level histogram ============
__global__ __launch_bounds__(1024) void select_kernel(const float* __restrict__ conf,
                                                      unsigned long long* __restrict__ pairs,
                                                      int* __restrict__ mcount) {
#pragma clang fp contract(off)
  const int img = blockIdx.x;
  const int tid = threadIdx.x;
  __shared__ unsigned int h[NSUB][NBINS];
  __shared__ unsigned int scan[NBINS];
  __shared__ unsigned int s_b1, s_base, s_cutoff, s_cnt;

  const float* cbase = conf + (size_t)img * NPRIORS * 2 + 1;  // class-1 scores, stride 2
  const int sub = (tid >> 6) & (NSUB - 1);

  // ---- pass 1: histogram on u>>22 ----
  for (int i = tid; i < NSUB * NBINS; i += 1024) ((unsigned int*)h)[i] = 0;
  __syncthreads();
  for (int p = tid; p < NPRIORS; p += 1024) {
    float sc = cbase[(size_t)p * 2];
    unsigned int u = (sc > 0.05f) ? (__float_as_uint(sc) | 0x80000000u) : 0u;
    if (u) atomicAdd(&h[sub][u >> 22], 1u);
  }
  __syncthreads();
  unsigned int cnt = 0;
  for (int s = 0; s < NSUB; s++) cnt += h[s][tid];
  scan[tid] = cnt;
  if (tid == 0) s_b1 = 0xFFFFFFFFu;
  __syncthreads();
  // inclusive suffix scan (Hillis-Steele)
  for (int off = 1; off < NBINS; off <<= 1) {
    unsigned int v = (tid + off < NBINS) ? scan[tid + off] : 0u;
    __syncthreads();
    scan[tid] += v;
    __syncthreads();
  }
  unsigned int sfx = scan[tid];
  if (sfx >= KSEL && (sfx - cnt) < KSEL) { s_b1 = (unsigned int)tid; s_base = sfx - cnt; }
  __syncthreads();
  unsigned int b1 = s_b1;
  unsigned int cutoff;
  if (b1 == 0xFFFFFFFFu) {
    cutoff = 1u;  // fewer than KSEL above threshold: take all u>0
  } else {
    // ---- pass 2: refine boundary bin on bits (u>>12)&1023 ----
    for (int i = tid; i < NSUB * NBINS; i += 1024) ((unsigned int*)h)[i] = 0;
    __syncthreads();
    for (int p = tid; p < NPRIORS; p += 1024) {
      float sc = cbase[(size_t)p * 2];
      unsigned int u = (sc > 0.05f) ? (__float_as_uint(sc) | 0x80000000u) : 0u;
      if (u && (u >> 22) == b1) atomicAdd(&h[sub][(u >> 12) & (NBINS - 1)], 1u);
    }
    __syncthreads();
    unsigned int cnt2 = 0;
    for (int s = 0; s < NSUB; s++) cnt2 += h[s][tid];
    scan[tid] = cnt2;
    __syncthreads();
    for (int off = 1; off < NBINS; off <<= 1) {
      unsigned int v = (tid + off < NBINS) ? scan[tid + off] : 0u;
      __syncthreads();
      scan[tid] += v;
      __syncthreads();
    }
    unsigned int base = s_base;
    unsigned int sfx2 = scan[tid];
    if (base + sfx2 >= KSEL && (base + sfx2 - cnt2) < KSEL)
      s_cutoff = (b1 << 22) | ((unsigned int)tid << 12);
    __syncthreads();
    cutoff = s_cutoff;
  }

  // ---- pass 3: compact (u, flipped idx) keys ----
  if (tid == 0) s_cnt = 0;
  __syncthreads();
  unsigned long long* mypairs = pairs + (size_t)img * SORTN;
  for (int p = tid; p < NPRIORS; p += 1024) {
    float sc = cbase[(size_t)p * 2];
    unsigned int u = (sc > 0.05f) ? (__float_as_uint(sc) | 0x80000000u) : 0u;
    if (u >= cutoff && u != 0u) {
      unsigned int pos = atomicAdd(&s_cnt, 1u);
      if (pos < SORTN)
        mypairs[pos] = ((unsigned long long)u << 32) | (unsigned long long)(0xFFFFFFFFu - (unsigned int)p);
    }
  }
  __syncthreads();
  if (tid == 0) mcount[img] = (int)min(s_cnt, (unsigned int)SORTN);
}

// ============ Kernel 2: bitonic sort (desc) + SSD box decode ============
__global__ __launch_bounds__(1024) void sort_decode_kernel(const unsigned long long* __restrict__ pairs,
                                                           const int* __restrict__ mcount,
                                                           const float* __restrict__ loc,
                                                           const float* __restrict__ prior,
                                                           float4* __restrict__ sboxes,
                                                           float* __restrict__ sscores) {
#pragma clang fp contract(off)
  const int img = blockIdx.x;
  const int tid = threadIdx.x;
  __shared__ unsigned long long key[SORTN];  // 64 KB
  const int M = mcount[img];
  const unsigned long long* mypairs = pairs + (size_t)img * SORTN;
  for (int i = tid; i < SORTN; i += 1024) key[i] = (i < M) ? mypairs[i] : 0ULL;
  __syncthreads();

  // bitonic sort, descending (padding key 0 sinks to the end)
  for (int k = 2; k <= SORTN; k <<= 1) {
    for (int j = k >> 1; j > 0; j >>= 1) {
      for (int i = tid; i < SORTN; i += 1024) {
        int l = i ^ j;
        if (l > i) {
          unsigned long long a = key[i], b = key[l];
          bool sw = ((i & k) == 0) ? (a < b) : (a > b);
          if (sw) { key[i] = b; key[l] = a; }
        }
      }
      __syncthreads();
    }
  }

  // decode top KSEL: exact reference arithmetic, fp32, no contraction
  for (int i = tid; i < KSEL; i += 1024) {
    unsigned long long kk = key[i];
    float score;
    float4 box;
    if (kk != 0ULL) {
      unsigned int u = (unsigned int)(kk >> 32);
      unsigned int p = 0xFFFFFFFFu - (unsigned int)(kk & 0xFFFFFFFFu);
      score = __uint_as_float(u & 0x7FFFFFFFu);
      const float* lp = loc + ((size_t)img * NPRIORS + p) * 4;
      const float* pp = prior + (size_t)p * 4;
      float l0 = lp[0], l1 = lp[1], l2 = lp[2], l3 = lp[3];
      float px = pp[0], py = pp[1], pw = pp[2], ph = pp[3];
      float cx = px + (l0 * 0.1f) * pw;
      float cy = py + (l1 * 0.1f) * ph;
      // double exp rounded to f32 == correctly-rounded float exp (matches np/glibc expf)
      float w = pw * (float)exp((double)(l2 * 0.2f));
      float hh = ph * (float)exp((double)(l3 * 0.2f));
      box.x = cx - w * 0.5f;
      box.y = cy - hh * 0.5f;
      box.z = cx + w * 0.5f;
      box.w = cy + hh * 0.5f;
    } else {
      score = -1e9f;
      box = make_float4(0.f, 0.f, 0.f, 0.f);
    }
    sboxes[(size_t)img * KSEL + i] = box;
    sscores[(size_t)img * KSEL + i] = score;
  }
}

// ============ Kernel 3: greedy NMS (head-pointer over alive bitmask) ============
__global__ __launch_bounds__(1024) void nms_kernel(const float4* __restrict__ sboxes,
                                                   const float* __restrict__ sscores,
                                                   const int* __restrict__ mcount,
                                                   float* __restrict__ out) {
#pragma clang fp contract(off)
  const int img = blockIdx.x;
  const int tid = threadIdx.x;
  __shared__ unsigned long long amask[NMASK];
  __shared__ int s_cur;
  const int V = min(mcount[img], KSEL);

  for (int w = tid; w < NMASK; w += 1024) {
    int lo = w * 64;
    unsigned long long m;
    if (V >= lo + 64)      m = ~0ULL;
    else if (V <= lo)      m = 0ULL;
    else                   m = (~0ULL) >> (64 - (V - lo));
    amask[w] = m;
  }

  const float4* bb = sboxes + (size_t)img * KSEL;
  const float* ss = sscores + (size_t)img * KSEL;
  float4 mybox[5];
  bool alive[5];
  for (int s = 0; s < 5; s++) {
    int c = tid + (s << 10);
    if (c < V) { mybox[s] = bb[c]; alive[s] = true; }
    else       { mybox[s] = make_float4(0.f, 0.f, 0.f, 0.f); alive[s] = false; }
  }
  float* obase = out + (size_t)img * (2 * TOPK * 5) + (TOPK * 5);  // class 1 slab
  int head = 0;  // only meaningful on tid 0
  __syncthreads();

  for (int k = 0; k < TOPK; k++) {
    if (tid == 0) {
      int idx = -1;
      int w = head >> 6;
      while (w < NMASK) {
        unsigned long long m = amask[w];
        if (m) { idx = (w << 6) + __builtin_ctzll(m); break; }
        w++;
      }
      if (idx >= 0) {
        amask[idx >> 6] &= ~(1ULL << (idx & 63));
        head = idx + 1;
      }
      s_cur = idx;
    }
    __syncthreads();
    const int cidx = s_cur;
    if (cidx < 0) break;  // block-uniform
    const float4 pb = bb[cidx];
    if (tid == 0) {
      float* o = obase + k * 5;
      o[0] = ss[cidx]; o[1] = pb.x; o[2] = pb.y; o[3] = pb.z; o[4] = pb.w;
    }
    const float pArea = (pb.z - pb.x) * (pb.w - pb.y);
    for (int s = 0; s < 5; s++) {
      int c = tid + (s << 10);
      if (alive[s] && c > cidx) {
        float4 b = mybox[s];
        float ltx = fmaxf(pb.x, b.x), lty = fmaxf(pb.y, b.y);
        float rbx = fminf(pb.z, b.z), rby = fminf(pb.w, b.w);
        float ww = fmaxf(rbx - ltx, 0.0f), hh2 = fmaxf(rby - lty, 0.0f);
        float inter = ww * hh2;
        float areaB = (b.z - b.x) * (b.w - b.y);
        float uni = pArea + areaB - inter;
        float iou = inter / fmaxf(uni, 1e-12f);
        if (iou > 0.3f) {
          alive[s] = false;
          atomicAnd(&amask[c >> 6], ~(1ULL << (c & 63)));
        }
      }
    }
    __syncthreads();
  }
}

extern "C" void kernel_launch(void* const* d_in, const int* in_sizes, int n_in,
                              void* d_out, int out_size, void* d_ws, size_t ws_size,
                              hipStream_t stream) {
  const float* loc = (const float*)d_in[0];    // [16, 131072, 4]
  const float* conf = (const float*)d_in[1];   // [16*131072, 2]
  const float* prior = (const float*)d_in[2];  // [131072, 4]
  float* out = (float*)d_out;                  // [16, 2, 750, 5]

  char* ws = (char*)d_ws;
  unsigned long long* pairs = (unsigned long long*)(ws + WS_PAIRS);
  int* mcount = (int*)(ws + WS_MCNT);
  float4* sboxes = (float4*)(ws + WS_BOXES);
  float* sscores = (float*)(ws + WS_SCORES);

  // output is mostly zeros (background class + invalid rows)
  hipMemsetAsync(d_out, 0, (size_t)out_size * sizeof(float), stream);

  select_kernel<<<NIMG, 1024, 0, stream>>>(conf, pairs, mcount);
  sort_decode_kernel<<<NIMG, 1024, 0, stream>>>(pairs, mcount, loc, prior, sboxes, sscores);
  nms_kernel<<<NIMG, 1024, 0, stream>>>(sboxes, sscores, mcount, out);
}